// Round 4
// baseline (239.700 us; speedup 1.0000x reference)
//
#include <hip/hip_runtime.h>

// ---------------- types ----------------
typedef __attribute__((ext_vector_type(8)))  __bf16 bf16x8;
typedef __attribute__((ext_vector_type(16))) float  f32x16;

struct U4 { unsigned int x, y, z, w; };

static __device__ __forceinline__ unsigned short f2bf(float f){
  unsigned int u = __builtin_bit_cast(unsigned int, f);
  u += 0x7fffu + ((u >> 16) & 1u);          // round-to-nearest-even
  return (unsigned short)(u >> 16);
}

static __device__ __forceinline__ unsigned pk2(float lo, float hi){
  return (unsigned)f2bf(lo) | ((unsigned)f2bf(hi) << 16);
}

static __device__ __forceinline__ bf16x8 ldfrag(const void* p){
  U4 v = *(const U4*)p;                      // ds_read_b128
  return __builtin_bit_cast(bf16x8, v);
}

static __device__ __forceinline__ f32x16 mfma32(bf16x8 a, bf16x8 b, f32x16 c){
  return __builtin_amdgcn_mfma_f32_32x32x16_bf16(a, b, c, 0, 0, 0);
}

static __device__ __forceinline__ f32x16 zero16(){
  f32x16 z;
#pragma unroll
  for (int i = 0; i < 16; ++i) z[i] = 0.0f;
  return z;
}

// half-wave swap: new_a[l>=32] = b[l-32]; new_b[l<32] = a[l+32]
static __device__ __forceinline__ void swap32(unsigned &a, unsigned &b){
  unsigned sa = (unsigned)__shfl_xor((int)a, 32, 64);
  unsigned sb = (unsigned)__shfl_xor((int)b, 32, 64);
  int l = (int)(threadIdx.x & 63);
  unsigned na = (l < 32) ? a : sb;
  unsigned nb = (l < 32) ? sa : b;
  a = na; b = nb;
}

// ---------------- constants ----------------
// B=8 T=2048 E=8 D=128 H=512 ; tokens = 16384
#define IMG_EC  49152           // 48 KB per (expert, chunk): wg 16K | wu 16K | wd 16K

// ---------------- P1: absmean sums ----------------
__global__ void k_gamma(const float* __restrict__ gw, const float* __restrict__ uw,
                        const float* __restrict__ dw, float* __restrict__ sums){
  int t = blockIdx.y;
  const float* w = (t == 0) ? gw : (t == 1 ? uw : dw);
  int base = blockIdx.x * 2048 + threadIdx.x * 8;
  float4 a = *(const float4*)(w + base);
  float4 b = *(const float4*)(w + base + 4);
  float s = fabsf(a.x)+fabsf(a.y)+fabsf(a.z)+fabsf(a.w)
          + fabsf(b.x)+fabsf(b.y)+fabsf(b.z)+fabsf(b.w);
#pragma unroll
  for (int o = 32; o; o >>= 1) s += __shfl_xor(s, o);
  if ((threadIdx.x & 63) == 0) atomicAdd(&sums[t], s);
}

// ---------------- P2: ternary quantize -> fragment-ordered bf16 images ----------------
// gate/up image per (e,c): [ht(2)][ks(8)][lane(64)][16B]  (frag: h = ht*32+(L&31), k d = ks*16+(L>>5)*8+j)
// down    image per (e,c): [dt(4)][ks'(4)][lane(64)][16B] (frag: d = dt*32+(L&31), k h = c*64+ks'*16+(L>>5)*8+j)
__global__ void k_quant(const float* __restrict__ gw, const float* __restrict__ uw,
                        const float* __restrict__ dw, const float* __restrict__ sums,
                        unsigned char* __restrict__ img){
  int b  = blockIdx.x;
  int tt = b % 3;
  int c  = (b / 3) & 7;
  int e  = b / 24;
  const float* w = (tt == 0) ? gw : (tt == 1 ? uw : dw);
  float inv = 1.0f / (sums[tt] * (1.0f / 524288.0f) + 1e-8f);
  unsigned char* dst = img + (size_t)(e * 8 + c) * IMG_EC + tt * 16384;
#pragma unroll
  for (int i = 0; i < 4; ++i){
    int grp = threadIdx.x + i * 256;      // 0..1023 (16B groups of 16KB)
    int L = grp & 63, blkid = grp >> 6;
    int srcoff;
    if (tt < 2){
      int ht = blkid >> 3, ks = blkid & 7;
      int h  = c * 64 + ht * 32 + (L & 31);
      int dd = ks * 16 + (L >> 5) * 8;
      srcoff = (e * 512 + h) * 128 + dd;
    } else {
      int dt = blkid >> 2, ksp = blkid & 3;
      int d0 = dt * 32 + (L & 31);
      int h  = c * 64 + ksp * 16 + (L >> 5) * 8;
      srcoff = (e * 128 + d0) * 512 + h;
    }
    float4 f0 = *(const float4*)(w + srcoff);
    float4 f1 = *(const float4*)(w + srcoff + 4);
    float v[8] = {f0.x,f0.y,f0.z,f0.w,f1.x,f1.y,f1.z,f1.w};
    unsigned int o[4];
#pragma unroll
    for (int j = 0; j < 4; ++j){
      float q0 = fminf(1.0f, fmaxf(-1.0f, rintf(v[2*j]   * inv)));
      float q1 = fminf(1.0f, fmaxf(-1.0f, rintf(v[2*j+1] * inv)));
      o[j] = (unsigned int)f2bf(q0) | ((unsigned int)f2bf(q1) << 16);
    }
    *(U4*)(dst + grp * 16) = U4{o[0], o[1], o[2], o[3]};
  }
}

// ---------------- main fused kernel ----------------
// grid (64, 8), 512 threads (8 waves), wave owns 32 tokens.
// Cross-chunk software pipeline: iteration i runs mm1(chunk i) AND mm2(chunk
// i-1) (independent -> silu VALU overlaps mm2 MFMAs). Weights staged
// global->reg->ds_write; gate/up double-buffered, down triple-buffered so the
// write never collides with mm2's lagging reads. One barrier per iteration.
__global__ __attribute__((amdgpu_waves_per_eu(2, 2))) __launch_bounds__(512)
void k_moe(const float* __restrict__ x, const float* __restrict__ ew,
           const float* __restrict__ sums, const unsigned char* __restrict__ img,
           float* __restrict__ out){
  extern __shared__ char smem[];            // gu 2x32K | dn 3x16K = 112K
  char* GU = smem;
  char* DN = smem + 65536;
  const int tile = blockIdx.x;
  const int e    = blockIdx.y;
  const int tid  = threadIdx.x;
  const int lane = tid & 63;
  const int wid  = tid >> 6;
  const int col  = lane & 31;
  const int hi   = lane >> 5;
  const int token = tile * 256 + wid * 32 + col;

  const float gg  = sums[0] * (1.0f/524288.0f) + 1e-8f;
  const float gu  = sums[1] * (1.0f/524288.0f) + 1e-8f;
  const float gdn = sums[2] * (1.0f/524288.0f) + 1e-8f;

  const unsigned char* wsrc0 = img + (size_t)e * 8 * IMG_EC;

  // ---- x fragments in registers: lane holds x[token][ks*16 + hi*8 .. +8) ----
  const float* xrow = x + ((size_t)token * 8 + e) * 128 + hi * 8;
  bf16x8 xf[8];
#pragma unroll
  for (int ks = 0; ks < 8; ++ks){
    float4 f0 = *(const float4*)(xrow + ks * 16);
    float4 f1 = *(const float4*)(xrow + ks * 16 + 4);
    U4 u{pk2(f0.x,f0.y), pk2(f0.z,f0.w), pk2(f1.x,f1.y), pk2(f1.z,f1.w)};
    xf[ks] = __builtin_bit_cast(bf16x8, u);
  }

  // ---- prologue: chunk0 -> LDS, chunk1 -> regs ----
  U4 sg[4], sd[2];
#pragma unroll
  for (int k = 0; k < 4; ++k) sg[k] = *(const U4*)(wsrc0 + tid*16 + k*8192);
#pragma unroll
  for (int k = 0; k < 2; ++k) sd[k] = *(const U4*)(wsrc0 + 32768 + tid*16 + k*8192);
#pragma unroll
  for (int k = 0; k < 4; ++k) *(U4*)(GU + tid*16 + k*8192) = sg[k];
#pragma unroll
  for (int k = 0; k < 2; ++k) *(U4*)(DN + tid*16 + k*8192) = sd[k];
#pragma unroll
  for (int k = 0; k < 4; ++k) sg[k] = *(const U4*)(wsrc0 + IMG_EC + tid*16 + k*8192);
#pragma unroll
  for (int k = 0; k < 2; ++k) sd[k] = *(const U4*)(wsrc0 + IMG_EC + 32768 + tid*16 + k*8192);
  __syncthreads();

  f32x16 O0 = zero16(), O1 = zero16(), O2 = zero16(), O3 = zero16();
  bf16x8 hf[2][4];

#pragma unroll
  for (int i = 0; i < 9; ++i){
    // ---- stage chunk i+1 (regs -> LDS); buffers idle by pipeline design ----
    if (i < 7){
      char* gub = GU + ((i+1)&1) * 32768;
      char* dnb = DN + ((i+1)%3) * 16384;
#pragma unroll
      for (int k = 0; k < 4; ++k) *(U4*)(gub + tid*16 + k*8192) = sg[k];
#pragma unroll
      for (int k = 0; k < 2; ++k) *(U4*)(dnb + tid*16 + k*8192) = sd[k];
    }
    // ---- issue loads for chunk i+2 (consumed next iteration) ----
    if (i < 6){
      const unsigned char* cs = wsrc0 + (size_t)(i+2) * IMG_EC;
#pragma unroll
      for (int k = 0; k < 4; ++k) sg[k] = *(const U4*)(cs + tid*16 + k*8192);
#pragma unroll
      for (int k = 0; k < 2; ++k) sd[k] = *(const U4*)(cs + 32768 + tid*16 + k*8192);
    }

    if (i < 8){
      // ---- mm1(i) per 32-h half, with mm2(i-1) half interleaved ----
      const char* gub = GU + (i&1) * 32768;
      const char* dnb = DN + ((i-1+3)%3) * 16384;   // only used when i>=1
#pragma unroll
      for (int ht = 0; ht < 2; ++ht){
        f32x16 Cg = zero16(), Cu = zero16();
#pragma unroll
        for (int ks = 0; ks < 8; ++ks){
          bf16x8 ag = ldfrag(gub +         ((ht*8 + ks)*64 + lane)*16);
          bf16x8 au = ldfrag(gub + 16384 + ((ht*8 + ks)*64 + lane)*16);
          Cg = mfma32(ag, xf[ks], Cg);
          Cu = mfma32(au, xf[ks], Cu);
        }
        // mm2(i-1), half: dt = ht*2, ht*2+1 — independent of this mm1
        if (i >= 1){
#pragma unroll
          for (int ks2 = 0; ks2 < 4; ++ks2){
            bf16x8 dA = ldfrag(dnb + (((ht*2+0)*4 + ks2)*64 + lane)*16);
            bf16x8 dB = ldfrag(dnb + (((ht*2+1)*4 + ks2)*64 + lane)*16);
            if (ht == 0){
              O0 = mfma32(dA, hf[(i-1)&1][ks2], O0);
              O1 = mfma32(dB, hf[(i-1)&1][ks2], O1);
            } else {
              O2 = mfma32(dA, hf[(i-1)&1][ks2], O2);
              O3 = mfma32(dB, hf[(i-1)&1][ks2], O3);
            }
          }
        }
        // silu for this half -> hf (overlaps mm2 MFMAs above)
#pragma unroll
        for (int s = 0; s < 2; ++s){
          float h[8];
#pragma unroll
          for (int j = 0; j < 8; ++j){
            float gv = Cg[s*8 + j] * gg;
            float uv = Cu[s*8 + j] * gu;
            h[j] = gv * __builtin_amdgcn_rcpf(1.0f + __expf(-gv)) * uv;
          }
          unsigned w0 = pk2(h[0], h[1]);
          unsigned w1 = pk2(h[2], h[3]);
          unsigned w2 = pk2(h[4], h[5]);
          unsigned w3 = pk2(h[6], h[7]);
          swap32(w0, w2);
          swap32(w1, w3);
          U4 u{w0, w1, w2, w3};
          hf[i&1][ht*2 + s] = __builtin_bit_cast(bf16x8, u);
        }
      }
    } else {
      // ---- i == 8: drain — final mm2(7) only ----
      const char* dnb = DN + (7%3) * 16384;
#pragma unroll
      for (int ks2 = 0; ks2 < 4; ++ks2){
        bf16x8 d0 = ldfrag(dnb + ((0*4 + ks2)*64 + lane)*16);
        bf16x8 d1 = ldfrag(dnb + ((1*4 + ks2)*64 + lane)*16);
        bf16x8 d2 = ldfrag(dnb + ((2*4 + ks2)*64 + lane)*16);
        bf16x8 d3 = ldfrag(dnb + ((3*4 + ks2)*64 + lane)*16);
        O0 = mfma32(d0, hf[1][ks2], O0);
        O1 = mfma32(d1, hf[1][ks2], O1);
        O2 = mfma32(d2, hf[1][ks2], O2);
        O3 = mfma32(d3, hf[1][ks2], O3);
      }
    }
    if (i < 8) __syncthreads();
  }

  // ---- epilogue: lane holds one token, 64 d-values; float4 stores ----
  const float osc = gdn * ew[token * 8 + e];
  float* orow = out + ((size_t)token * 8 + e) * 128 + hi * 4;
#pragma unroll
  for (int dt = 0; dt < 4; ++dt){
    const f32x16& O = dt == 0 ? O0 : dt == 1 ? O1 : dt == 2 ? O2 : O3;
#pragma unroll
    for (int q = 0; q < 4; ++q){
      float4 v{O[q*4+0]*osc, O[q*4+1]*osc, O[q*4+2]*osc, O[q*4+3]*osc};
      *(float4*)(orow + dt * 32 + q * 8) = v;   // d = dt*32 + q*8 + hi*4 + j
    }
  }
}

// ---------------- launcher ----------------
extern "C" void kernel_launch(void* const* d_in, const int* in_sizes, int n_in,
                              void* d_out, int out_size, void* d_ws, size_t ws_size,
                              hipStream_t stream){
  const float* x  = (const float*)d_in[0];
  const float* ew = (const float*)d_in[1];
  const float* gw = (const float*)d_in[2];
  const float* uw = (const float*)d_in[3];
  const float* dw = (const float*)d_in[4];
  float* out = (float*)d_out;

  float* sums = (float*)d_ws;
  unsigned char* img = (unsigned char*)d_ws + 256;

  hipMemsetAsync(d_ws, 0, 16, stream);
  k_gamma<<<dim3(256, 3), 256, 0, stream>>>(gw, uw, dw, sums);
  k_quant<<<dim3(192), 256, 0, stream>>>(gw, uw, dw, sums, img);
  k_moe<<<dim3(64, 8), 512, 114688, stream>>>(x, ew, sums, img, out);
}

// Round 5
// 178.518 us; speedup vs baseline: 1.3427x; 1.3427x over previous
//
#include <hip/hip_runtime.h>

// ---------------- types ----------------
typedef __attribute__((ext_vector_type(8)))  __bf16 bf16x8;
typedef __attribute__((ext_vector_type(16))) float  f32x16;

struct U4 { unsigned int x, y, z, w; };

// pack two floats to bf16x2 (compiler fuses to v_cvt_pk_bf16_f32, RNE)
static __device__ __forceinline__ unsigned pk2(float lo, float hi){
  unsigned short ul = __builtin_bit_cast(unsigned short, (__bf16)lo);
  unsigned short uh = __builtin_bit_cast(unsigned short, (__bf16)hi);
  return (unsigned)ul | ((unsigned)uh << 16);
}

static __device__ __forceinline__ bf16x8 ldfrag(const void* p){
  U4 v = *(const U4*)p;                      // ds_read_b128
  return __builtin_bit_cast(bf16x8, v);
}

static __device__ __forceinline__ f32x16 mfma32(bf16x8 a, bf16x8 b, f32x16 c){
  return __builtin_amdgcn_mfma_f32_32x32x16_bf16(a, b, c, 0, 0, 0);
}

static __device__ __forceinline__ f32x16 zero16(){
  f32x16 z;
#pragma unroll
  for (int i = 0; i < 16; ++i) z[i] = 0.0f;
  return z;
}

// half-wave swap via permlane (VALU-only, no LDS):
// new_a = {a.lo, b.lo}, new_b = {a.hi, b.hi} in lane space
static __device__ __forceinline__ void swap32(unsigned &a, unsigned &b){
  asm volatile("v_permlane32_swap_b32 %0, %1" : "+v"(a), "+v"(b));
}

// ---------------- constants ----------------
// B=8 T=2048 E=8 D=128 H=512 ; tokens = 16384
#define IMG_EC  49152           // 48 KB per (expert, chunk): wg 16K | wu 16K | wd 16K

// ---------------- P1: absmean sums ----------------
__global__ void k_gamma(const float* __restrict__ gw, const float* __restrict__ uw,
                        const float* __restrict__ dw, float* __restrict__ sums){
  int t = blockIdx.y;
  const float* w = (t == 0) ? gw : (t == 1 ? uw : dw);
  int base = blockIdx.x * 2048 + threadIdx.x * 8;
  float4 a = *(const float4*)(w + base);
  float4 b = *(const float4*)(w + base + 4);
  float s = fabsf(a.x)+fabsf(a.y)+fabsf(a.z)+fabsf(a.w)
          + fabsf(b.x)+fabsf(b.y)+fabsf(b.z)+fabsf(b.w);
#pragma unroll
  for (int o = 32; o; o >>= 1) s += __shfl_xor(s, o);
  if ((threadIdx.x & 63) == 0) atomicAdd(&sums[t], s);
}

// ---------------- P2: ternary quantize -> fragment-ordered bf16 images ----------------
// gate/up image per (e,c): [ht(2)][ks(8)][lane(64)][16B]  (frag: h = ht*32+(L&31), k d = ks*16+(L>>5)*8+j)
// down    image per (e,c): [dt(4)][ks'(4)][lane(64)][16B] (frag: d = dt*32+(L&31), k h = c*64+ks'*16+(L>>5)*8+j)
__global__ void k_quant(const float* __restrict__ gw, const float* __restrict__ uw,
                        const float* __restrict__ dw, const float* __restrict__ sums,
                        unsigned char* __restrict__ img){
  int b  = blockIdx.x;
  int tt = b % 3;
  int c  = (b / 3) & 7;
  int e  = b / 24;
  const float* w = (tt == 0) ? gw : (tt == 1 ? uw : dw);
  float inv = 1.0f / (sums[tt] * (1.0f / 524288.0f) + 1e-8f);
  unsigned char* dst = img + (size_t)(e * 8 + c) * IMG_EC + tt * 16384;
#pragma unroll
  for (int i = 0; i < 4; ++i){
    int grp = threadIdx.x + i * 256;      // 0..1023 (16B groups of 16KB)
    int L = grp & 63, blkid = grp >> 6;
    int srcoff;
    if (tt < 2){
      int ht = blkid >> 3, ks = blkid & 7;
      int h  = c * 64 + ht * 32 + (L & 31);
      int dd = ks * 16 + (L >> 5) * 8;
      srcoff = (e * 512 + h) * 128 + dd;
    } else {
      int dt = blkid >> 2, ksp = blkid & 3;
      int d0 = dt * 32 + (L & 31);
      int h  = c * 64 + ksp * 16 + (L >> 5) * 8;
      srcoff = (e * 128 + d0) * 512 + h;
    }
    float4 f0 = *(const float4*)(w + srcoff);
    float4 f1 = *(const float4*)(w + srcoff + 4);
    float v[8] = {f0.x,f0.y,f0.z,f0.w,f1.x,f1.y,f1.z,f1.w};
    unsigned int o[4];
#pragma unroll
    for (int j = 0; j < 4; ++j){
      float q0 = fminf(1.0f, fmaxf(-1.0f, rintf(v[2*j]   * inv)));
      float q1 = fminf(1.0f, fmaxf(-1.0f, rintf(v[2*j+1] * inv)));
      o[j] = pk2(q0, q1);
    }
    *(U4*)(dst + grp * 16) = U4{o[0], o[1], o[2], o[3]};
  }
}

// ---------------- main fused kernel ----------------
// grid (64, 8), 512 threads (8 waves), wave owns 32 tokens.
// Swapped mm1: C = mfma(W, x^T) -> col = token; hidden stays in registers
// (cvt_pk + permlane32_swap) feeding mm2 B-frags directly.
// Staging: global->reg (chunk c+1, in flight under compute) -> ds_write in a
// barrier-separated phase (LDS write stream never concurrent with the read
// stream -- the conflict-free pattern measured in R2: 5.9e5 vs 4e7).
__global__ __launch_bounds__(512)
void k_moe(const float* __restrict__ x, const float* __restrict__ ew,
           const float* __restrict__ sums, const unsigned char* __restrict__ img,
           float* __restrict__ out){
  __shared__ char WB[49152];
  const int tile = blockIdx.x;
  const int e    = blockIdx.y;
  const int tid  = threadIdx.x;
  const int lane = tid & 63;
  const int wid  = tid >> 6;
  const int col  = lane & 31;
  const int hi   = lane >> 5;
  const int token = tile * 256 + wid * 32 + col;

  const float gg  = sums[0] * (1.0f/524288.0f) + 1e-8f;
  const float gu  = sums[1] * (1.0f/524288.0f) + 1e-8f;
  const float gdn = sums[2] * (1.0f/524288.0f) + 1e-8f;

  const unsigned char* wsrc0 = img + (size_t)e * 8 * IMG_EC;

  // ---- preload chunk 0 weights into registers ----
  U4 stg[6];
#pragma unroll
  for (int k = 0; k < 6; ++k)
    stg[k] = *(const U4*)(wsrc0 + tid * 16 + k * 8192);

  // ---- x fragments in registers: lane holds x[token][ks*16 + hi*8 .. +8) ----
  const float* xrow = x + ((size_t)token * 8 + e) * 128 + hi * 8;
  bf16x8 xf[8];
#pragma unroll
  for (int ks = 0; ks < 8; ++ks){
    float4 f0 = *(const float4*)(xrow + ks * 16);
    float4 f1 = *(const float4*)(xrow + ks * 16 + 4);
    U4 u{pk2(f0.x,f0.y), pk2(f0.z,f0.w), pk2(f1.x,f1.y), pk2(f1.z,f1.w)};
    xf[ks] = __builtin_bit_cast(bf16x8, u);
  }

  f32x16 O0 = zero16(), O1 = zero16(), O2 = zero16(), O3 = zero16();

  for (int c = 0; c < 8; ++c){
    // ---- write phase (barrier-separated from all reads) ----
    if (c) __syncthreads();                 // compute(c-1) done reading WB
#pragma unroll
    for (int k = 0; k < 6; ++k)
      *(U4*)(WB + tid * 16 + k * 8192) = stg[k];
    __syncthreads();                        // WB ready

    // ---- issue chunk c+1 loads; they fly under this chunk's compute ----
    if (c < 7){
      const unsigned char* cs = wsrc0 + (size_t)(c + 1) * IMG_EC;
#pragma unroll
      for (int k = 0; k < 6; ++k)
        stg[k] = *(const U4*)(cs + tid * 16 + k * 8192);
    }

    // ---- mm1 per 32-h half + silu -> hf (in-register hidden) ----
    bf16x8 hf[4];
#pragma unroll
    for (int ht = 0; ht < 2; ++ht){
      f32x16 Cg = zero16(), Cu = zero16();
#pragma unroll
      for (int ks = 0; ks < 8; ++ks){
        bf16x8 ag = ldfrag(WB +         ((ht*8 + ks)*64 + lane)*16);
        bf16x8 au = ldfrag(WB + 16384 + ((ht*8 + ks)*64 + lane)*16);
        Cg = mfma32(ag, xf[ks], Cg);
        Cu = mfma32(au, xf[ks], Cu);
      }
#pragma unroll
      for (int s = 0; s < 2; ++s){
        float h[8];
#pragma unroll
        for (int j = 0; j < 8; ++j){
          float gv = Cg[s*8 + j] * gg;
          float uv = Cu[s*8 + j] * gu;
          h[j] = gv * __builtin_amdgcn_rcpf(1.0f + __expf(-gv)) * uv;
        }
        unsigned w0 = pk2(h[0], h[1]);
        unsigned w1 = pk2(h[2], h[3]);
        unsigned w2 = pk2(h[4], h[5]);
        unsigned w3 = pk2(h[6], h[7]);
        swap32(w0, w2);
        swap32(w1, w3);
        U4 u{w0, w1, w2, w3};
        hf[ht*2 + s] = __builtin_bit_cast(bf16x8, u);
      }
    }

    // ---- mm2: O^T += W_down(d128 x h64) * hidden^T(h64 x t32) ----
#pragma unroll
    for (int ks2 = 0; ks2 < 4; ++ks2){
      bf16x8 d0 = ldfrag(WB + 32768 + ((0*4 + ks2)*64 + lane)*16);
      bf16x8 d1 = ldfrag(WB + 32768 + ((1*4 + ks2)*64 + lane)*16);
      bf16x8 d2 = ldfrag(WB + 32768 + ((2*4 + ks2)*64 + lane)*16);
      bf16x8 d3 = ldfrag(WB + 32768 + ((3*4 + ks2)*64 + lane)*16);
      O0 = mfma32(d0, hf[ks2], O0);
      O1 = mfma32(d1, hf[ks2], O1);
      O2 = mfma32(d2, hf[ks2], O2);
      O3 = mfma32(d3, hf[ks2], O3);
    }
  }

  // ---- epilogue: lane holds one token, 64 d-values; float4 stores ----
  const float osc = gdn * ew[token * 8 + e];
  float* orow = out + ((size_t)token * 8 + e) * 128 + hi * 4;
#pragma unroll
  for (int dt = 0; dt < 4; ++dt){
    const f32x16& O = dt == 0 ? O0 : dt == 1 ? O1 : dt == 2 ? O2 : O3;
#pragma unroll
    for (int q = 0; q < 4; ++q){
      float4 v{O[q*4+0]*osc, O[q*4+1]*osc, O[q*4+2]*osc, O[q*4+3]*osc};
      *(float4*)(orow + dt * 32 + q * 8) = v;   // d = dt*32 + q*8 + hi*4 + j
    }
  }
}

// ---------------- launcher ----------------
extern "C" void kernel_launch(void* const* d_in, const int* in_sizes, int n_in,
                              void* d_out, int out_size, void* d_ws, size_t ws_size,
                              hipStream_t stream){
  const float* x  = (const float*)d_in[0];
  const float* ew = (const float*)d_in[1];
  const float* gw = (const float*)d_in[2];
  const float* uw = (const float*)d_in[3];
  const float* dw = (const float*)d_in[4];
  float* out = (float*)d_out;

  float* sums = (float*)d_ws;
  unsigned char* img = (unsigned char*)d_ws + 256;

  hipMemsetAsync(d_ws, 0, 16, stream);
  k_gamma<<<dim3(256, 3), 256, 0, stream>>>(gw, uw, dw, sums);
  k_quant<<<dim3(192), 256, 0, stream>>>(gw, uw, dw, sums, img);
  k_moe<<<dim3(64, 8), 512, 0, stream>>>(x, ew, sums, img, out);
}

// Round 6
// 160.683 us; speedup vs baseline: 1.4918x; 1.1110x over previous
//
#include <hip/hip_runtime.h>

// ---------------- types ----------------
typedef __attribute__((ext_vector_type(8)))  __bf16 bf16x8;
typedef __attribute__((ext_vector_type(16))) float  f32x16;

struct U4 { unsigned int x, y, z, w; };

// pack two floats to bf16x2 (compiler fuses to v_cvt_pk_bf16_f32, RNE)
static __device__ __forceinline__ unsigned pk2(float lo, float hi){
  unsigned short ul = __builtin_bit_cast(unsigned short, (__bf16)lo);
  unsigned short uh = __builtin_bit_cast(unsigned short, (__bf16)hi);
  return (unsigned)ul | ((unsigned)uh << 16);
}

static __device__ __forceinline__ bf16x8 ldfrag(const void* p){
  U4 v = *(const U4*)p;                      // ds_read_b128
  return __builtin_bit_cast(bf16x8, v);
}

static __device__ __forceinline__ f32x16 mfma32(bf16x8 a, bf16x8 b, f32x16 c){
  return __builtin_amdgcn_mfma_f32_32x32x16_bf16(a, b, c, 0, 0, 0);
}

static __device__ __forceinline__ f32x16 zero16(){
  f32x16 z;
#pragma unroll
  for (int i = 0; i < 16; ++i) z[i] = 0.0f;
  return z;
}

// half-wave swap via permlane (VALU-only, no LDS):
// new_a = {a.lo, b.lo}, new_b = {a.hi, b.hi} in lane space
static __device__ __forceinline__ void swap32(unsigned &a, unsigned &b){
  asm volatile("v_permlane32_swap_b32 %0, %1" : "+v"(a), "+v"(b));
}

// ---------------- constants ----------------
// B=8 T=2048 E=8 D=128 H=512 ; token-expert rows = 131072
#define IMG_EC  49152           // 48 KB per (expert, chunk): wg 16K | wu 16K | wd 16K

// ---------------- P1: absmean sums ----------------
__global__ void k_gamma(const float* __restrict__ gw, const float* __restrict__ uw,
                        const float* __restrict__ dw, float* __restrict__ sums){
  int t = blockIdx.y;
  const float* w = (t == 0) ? gw : (t == 1 ? uw : dw);
  int base = blockIdx.x * 2048 + threadIdx.x * 8;
  float4 a = *(const float4*)(w + base);
  float4 b = *(const float4*)(w + base + 4);
  float s = fabsf(a.x)+fabsf(a.y)+fabsf(a.z)+fabsf(a.w)
          + fabsf(b.x)+fabsf(b.y)+fabsf(b.z)+fabsf(b.w);
#pragma unroll
  for (int o = 32; o; o >>= 1) s += __shfl_xor(s, o);
  if ((threadIdx.x & 63) == 0) atomicAdd(&sums[t], s);
}

// ---------------- P2: ternary quantize -> fragment-ordered bf16 images ----------------
// gate/up image per (e,c): [ht(2)][ks(8)][lane(64)][16B]  (frag: h = ht*32+(L&31), k d = ks*16+(L>>5)*8+j)
// down    image per (e,c): [dt(4)][ks'(4)][lane(64)][16B] (frag: d = dt*32+(L&31), k h = c*64+ks'*16+(L>>5)*8+j)
__global__ void k_quant(const float* __restrict__ gw, const float* __restrict__ uw,
                        const float* __restrict__ dw, const float* __restrict__ sums,
                        unsigned char* __restrict__ img){
  int b  = blockIdx.x;
  int tt = b % 3;
  int c  = (b / 3) & 7;
  int e  = b / 24;
  const float* w = (tt == 0) ? gw : (tt == 1 ? uw : dw);
  float inv = 1.0f / (sums[tt] * (1.0f / 524288.0f) + 1e-8f);
  unsigned char* dst = img + (size_t)(e * 8 + c) * IMG_EC + tt * 16384;
#pragma unroll
  for (int i = 0; i < 4; ++i){
    int grp = threadIdx.x + i * 256;      // 0..1023 (16B groups of 16KB)
    int L = grp & 63, blkid = grp >> 6;
    int srcoff;
    if (tt < 2){
      int ht = blkid >> 3, ks = blkid & 7;
      int h  = c * 64 + ht * 32 + (L & 31);
      int dd = ks * 16 + (L >> 5) * 8;
      srcoff = (e * 512 + h) * 128 + dd;
    } else {
      int dt = blkid >> 2, ksp = blkid & 3;
      int d0 = dt * 32 + (L & 31);
      int h  = c * 64 + ksp * 16 + (L >> 5) * 8;
      srcoff = (e * 128 + d0) * 512 + h;
    }
    float4 f0 = *(const float4*)(w + srcoff);
    float4 f1 = *(const float4*)(w + srcoff + 4);
    float v[8] = {f0.x,f0.y,f0.z,f0.w,f1.x,f1.y,f1.z,f1.w};
    unsigned int o[4];
#pragma unroll
    for (int j = 0; j < 4; ++j){
      float q0 = fminf(1.0f, fmaxf(-1.0f, rintf(v[2*j]   * inv)));
      float q1 = fminf(1.0f, fmaxf(-1.0f, rintf(v[2*j+1] * inv)));
      o[j] = pk2(q0, q1);
    }
    *(U4*)(dst + grp * 16) = U4{o[0], o[1], o[2], o[3]};
  }
}

// ---------------- main fused kernel ----------------
// grid (64, 8), 512 threads (8 waves), wave owns 32 tokens.
// Swapped mm1: C = mfma(W, x^T) -> col = token; hidden stays in registers
// (cvt_pk + permlane32_swap) feeding mm2 B-frags directly.
// Staging: global->reg (chunk c+1, in flight under compute) -> ds_write in a
// barrier-separated phase (R5: 0 bank conflicts).
// amdgpu_waves_per_eu(2,2): pin 2 waves/SIMD -> 256-VGPR budget, no spill
// (R3 evidence: only non-spilling config; R5's bare launch_bounds spilled
// 60 MB of scratch at VGPR=84).
__global__ __attribute__((amdgpu_waves_per_eu(2, 2))) __launch_bounds__(512)
void k_moe(const float* __restrict__ x, const float* __restrict__ ew,
           const float* __restrict__ sums, const unsigned char* __restrict__ img,
           float* __restrict__ out){
  __shared__ char WB[49152];
  const int tile = blockIdx.x;
  const int e    = blockIdx.y;
  const int tid  = threadIdx.x;
  const int lane = tid & 63;
  const int wid  = tid >> 6;
  const int col  = lane & 31;
  const int hi   = lane >> 5;
  const int token = tile * 256 + wid * 32 + col;

  const float gg  = sums[0] * (1.0f/524288.0f) + 1e-8f;
  const float gu  = sums[1] * (1.0f/524288.0f) + 1e-8f;
  const float gdn = sums[2] * (1.0f/524288.0f) + 1e-8f;

  const unsigned char* wsrc0 = img + (size_t)e * 8 * IMG_EC;

  // ---- preload chunk 0 weights into registers ----
  U4 stg[6];
#pragma unroll
  for (int k = 0; k < 6; ++k)
    stg[k] = *(const U4*)(wsrc0 + tid * 16 + k * 8192);

  // ---- x fragments in registers: lane holds x[token][ks*16 + hi*8 .. +8) ----
  const float* xrow = x + ((size_t)token * 8 + e) * 128 + hi * 8;
  bf16x8 xf[8];
#pragma unroll
  for (int ks = 0; ks < 8; ++ks){
    float4 f0 = *(const float4*)(xrow + ks * 16);
    float4 f1 = *(const float4*)(xrow + ks * 16 + 4);
    U4 u{pk2(f0.x,f0.y), pk2(f0.z,f0.w), pk2(f1.x,f1.y), pk2(f1.z,f1.w)};
    xf[ks] = __builtin_bit_cast(bf16x8, u);
  }

  f32x16 O0 = zero16(), O1 = zero16(), O2 = zero16(), O3 = zero16();

  for (int c = 0; c < 8; ++c){
    // ---- write phase (barrier-separated from all reads) ----
    if (c) __syncthreads();                 // compute(c-1) done reading WB
#pragma unroll
    for (int k = 0; k < 6; ++k)
      *(U4*)(WB + tid * 16 + k * 8192) = stg[k];
    __syncthreads();                        // WB ready

    // ---- issue chunk c+1 loads; they fly under this chunk's compute ----
    if (c < 7){
      const unsigned char* cs = wsrc0 + (size_t)(c + 1) * IMG_EC;
#pragma unroll
      for (int k = 0; k < 6; ++k)
        stg[k] = *(const U4*)(cs + tid * 16 + k * 8192);
    }

    // ---- mm1 per 32-h half + silu -> hf (in-register hidden) ----
    bf16x8 hf[4];
#pragma unroll
    for (int ht = 0; ht < 2; ++ht){
      f32x16 Cg = zero16(), Cu = zero16();
#pragma unroll
      for (int ks = 0; ks < 8; ++ks){
        bf16x8 ag = ldfrag(WB +         ((ht*8 + ks)*64 + lane)*16);
        bf16x8 au = ldfrag(WB + 16384 + ((ht*8 + ks)*64 + lane)*16);
        Cg = mfma32(ag, xf[ks], Cg);
        Cu = mfma32(au, xf[ks], Cu);
      }
#pragma unroll
      for (int s = 0; s < 2; ++s){
        float h[8];
#pragma unroll
        for (int j = 0; j < 8; ++j){
          float gv = Cg[s*8 + j] * gg;
          float uv = Cu[s*8 + j] * gu;
          h[j] = gv * __builtin_amdgcn_rcpf(1.0f + __expf(-gv)) * uv;
        }
        unsigned w0 = pk2(h[0], h[1]);
        unsigned w1 = pk2(h[2], h[3]);
        unsigned w2 = pk2(h[4], h[5]);
        unsigned w3 = pk2(h[6], h[7]);
        swap32(w0, w2);
        swap32(w1, w3);
        U4 u{w0, w1, w2, w3};
        hf[ht*2 + s] = __builtin_bit_cast(bf16x8, u);
      }
    }

    // ---- mm2: O^T += W_down(d128 x h64) * hidden^T(h64 x t32) ----
#pragma unroll
    for (int ks2 = 0; ks2 < 4; ++ks2){
      bf16x8 d0 = ldfrag(WB + 32768 + ((0*4 + ks2)*64 + lane)*16);
      bf16x8 d1 = ldfrag(WB + 32768 + ((1*4 + ks2)*64 + lane)*16);
      bf16x8 d2 = ldfrag(WB + 32768 + ((2*4 + ks2)*64 + lane)*16);
      bf16x8 d3 = ldfrag(WB + 32768 + ((3*4 + ks2)*64 + lane)*16);
      O0 = mfma32(d0, hf[ks2], O0);
      O1 = mfma32(d1, hf[ks2], O1);
      O2 = mfma32(d2, hf[ks2], O2);
      O3 = mfma32(d3, hf[ks2], O3);
    }
  }

  // ---- epilogue: lane holds one token, 64 d-values; float4 stores ----
  const float osc = gdn * ew[token * 8 + e];
  float* orow = out + ((size_t)token * 8 + e) * 128 + hi * 4;
#pragma unroll
  for (int dt = 0; dt < 4; ++dt){
    const f32x16& O = dt == 0 ? O0 : dt == 1 ? O1 : dt == 2 ? O2 : O3;
#pragma unroll
    for (int q = 0; q < 4; ++q){
      float4 v{O[q*4+0]*osc, O[q*4+1]*osc, O[q*4+2]*osc, O[q*4+3]*osc};
      *(float4*)(orow + dt * 32 + q * 8) = v;   // d = dt*32 + q*8 + hi*4 + j
    }
  }
}

// ---------------- launcher ----------------
extern "C" void kernel_launch(void* const* d_in, const int* in_sizes, int n_in,
                              void* d_out, int out_size, void* d_ws, size_t ws_size,
                              hipStream_t stream){
  const float* x  = (const float*)d_in[0];
  const float* ew = (const float*)d_in[1];
  const float* gw = (const float*)d_in[2];
  const float* uw = (const float*)d_in[3];
  const float* dw = (const float*)d_in[4];
  float* out = (float*)d_out;

  float* sums = (float*)d_ws;
  unsigned char* img = (unsigned char*)d_ws + 256;

  hipMemsetAsync(d_ws, 0, 16, stream);
  k_gamma<<<dim3(256, 3), 256, 0, stream>>>(gw, uw, dw, sums);
  k_quant<<<dim3(192), 256, 0, stream>>>(gw, uw, dw, sums, img);
  k_moe<<<dim3(64, 8), 512, 0, stream>>>(x, ew, sums, img, out);
}